// Round 14
// baseline (443.157 us; speedup 1.0000x reference)
//
#include <hip/hip_runtime.h>
#include <hip/hip_bf16.h>

#define S_DIM 256
#define I_DIM 64
#define O_DIM 64
#define BATCH 64
#define TT 2048
#define CHUNK 32
#define NCHUNK (TT / CHUNK)     // 64
#define NTASK (BATCH * TT / CHUNK)  // 4096

typedef __attribute__((ext_vector_type(8))) short short8v;      // 8 bf16
typedef _Float16 half8v __attribute__((ext_vector_type(8)));    // 8 fp16
typedef __attribute__((ext_vector_type(4))) float float4v;      // MFMA acc

__device__ inline unsigned short f2bf(float f) {
  unsigned x = __float_as_uint(f);
  unsigned r = (x + 0x7FFFu + ((x >> 16) & 1u)) >> 16;  // RNE
  return (unsigned short)r;
}
__device__ inline short bfr(float x) {
  __hip_bfloat16 h = __float2bfloat16(x);
  return __builtin_bit_cast(short, h);
}

// global -> LDS direct DMA, 16B per lane (dst = wave-uniform base + lane*16)
__device__ inline void gload16(const float* g, float* lds) {
  __builtin_amdgcn_global_load_lds(
      (const __attribute__((address_space(1))) unsigned int*)g,
      (__attribute__((address_space(3))) unsigned int*)lds, 16, 0, 0);
}

// ------------- matsq: dst = src @ src (256x256 f32, L2-resident) -------------
__global__ void k_matsq(const float* __restrict__ src, float* __restrict__ dst) {
  const int i = blockIdx.x;
  const int j = threadIdx.x;
  float acc = 0.f;
#pragma unroll 8
  for (int k = 0; k < 256; ++k) acc += src[i * 256 + k] * src[k * 256 + j];
  dst[i * 256 + j] = acc;
}

// ------------- f32 matrix -> fp16 hi/lo split -------------
__global__ void k_fsplit16(const float* __restrict__ src, _Float16* __restrict__ hi,
                           _Float16* __restrict__ lo) {
  int idx = blockIdx.x * 256 + threadIdx.x;
  float a = src[idx];
  _Float16 h = (_Float16)a;
  hi[idx] = h;
  lo[idx] = (_Float16)(a - (float)h);
}

// ------------- weight convert: Wd[n][k] = concat(s1,s2) rows, single bf16 -------------
__global__ void k_wcvt(const float* __restrict__ s1, const float* __restrict__ s2,
                       int K1, int K2, unsigned short* __restrict__ hi, int total) {
  int idx = blockIdx.x * 256 + threadIdx.x;
  if (idx >= total) return;
  int KT = K1 + K2;
  int n = idx / KT, k = idx - n * KT;
  float a = (k < K1) ? s1[n * K1 + k] : s2[n * K2 + (k - K1)];
  hi[idx] = f2bf(a);
}

// ---------------- single-shot LDS bf16 MFMA GEMM: out = [Asmall|Abig] @ W^T ----------------
// The ENTIRE 64-row A-slab (big K=256 -> 64 KB, small K=64 -> 16 KB) is staged via
// global_load_lds in one burst, then ONE barrier (its vmcnt(0) drain is exactly the
// "wait for all DMA" we want), then all 10 k-steps compute with no further syncs.
// Cross-block overlap (2 blocks/CU) keeps HBM streaming during compute phases.
// Granule-transposed LDS layout -> conflict-free b128 reads, no XOR (m173 pattern).
// SMALL_FIRST: W k-order is [small|big] (U-GEMM) vs [big|small] (obs-GEMM).
template <int N_TOT, bool SMALL_FIRST, int WIM, int WIN>
__global__ __launch_bounds__(256) void k_sgemm(
    const float* __restrict__ Abig, const float* __restrict__ Asmall,
    const unsigned short* __restrict__ W, float* __restrict__ out) {
  constexpr int KT = 320;
  constexpr int MF = 64 / WIM / 16;
  constexpr int NF = N_TOT / WIN / 16;
  extern __shared__ float ls[];  // 4*4096 (big) + 4096 (small) = 20480 f = 80 KB

  const int tid = threadIdx.x;
  const int wv = tid >> 6, lane = tid & 63;
  const int lo16 = lane & 15, hi4 = lane >> 4;
  const int wm = wv % WIM, wn = wv / WIM;
  const size_t R0 = (size_t)blockIdx.x * 64;
  const int C0 = wn * (N_TOT / WIN);

  // ---- stage everything: 20 gload16 per wave, fire-and-forget ----
#pragma unroll
  for (int kt = 0; kt < 4; ++kt)
#pragma unroll
    for (int c = 0; c < 4; ++c) {
      const int i = wv * 4 + c;
      const int s = i * 64 + lane;
      const int row = s & 63, g = s >> 6;
      gload16(Abig + (R0 + row) * 256 + kt * 64 + g * 4, &ls[kt * 4096 + i * 256]);
    }
#pragma unroll
  for (int c = 0; c < 4; ++c) {
    const int i = wv * 4 + c;
    const int s = i * 64 + lane;
    const int row = s & 63, g = s >> 6;
    gload16(Asmall + (R0 + row) * 64 + g * 4, &ls[16384 + i * 256]);
  }
  __syncthreads();  // single drain: all DMA landed, LDS visible block-wide

  float4v acc[MF][NF];
#pragma unroll
  for (int m = 0; m < MF; ++m)
#pragma unroll
    for (int n = 0; n < NF; ++n) acc[m][n] = (float4v){0.f, 0.f, 0.f, 0.f};

#pragma unroll
  for (int kw = 0; kw < 10; ++kw) {
    const bool is_small = SMALL_FIRST ? (kw < 2) : (kw >= 8);
    const int kl = SMALL_FIRST ? (is_small ? kw : kw - 2) : (is_small ? kw - 8 : kw);
    short8v ah[MF];
#pragma unroll
    for (int m = 0; m < MF; ++m) {
      const int row = wm * (64 / WIM) + m * 16 + lo16;
      const float* base =
          is_small ? &ls[16384 + ((kl * 8 + hi4 * 2) * 64 + row) * 4]
                   : &ls[(kl >> 1) * 4096 + (((kl & 1) * 8 + hi4 * 2) * 64 + row) * 4];
      float4 f0 = *reinterpret_cast<const float4*>(base);
      float4 f1 = *reinterpret_cast<const float4*>(base + 256);  // next granule g+1
#pragma unroll
      for (int j = 0; j < 4; ++j) {
        ah[m][j] = bfr((&f0.x)[j]);
        ah[m][j + 4] = bfr((&f1.x)[j]);
      }
    }
#pragma unroll
    for (int nf = 0; nf < NF; ++nf) {
      short8v w8 = *reinterpret_cast<const short8v*>(
          W + (size_t)(C0 + nf * 16 + lo16) * KT + kw * 32 + hi4 * 8);
#pragma unroll
      for (int m = 0; m < MF; ++m)
        acc[m][nf] = __builtin_amdgcn_mfma_f32_16x16x32_bf16(ah[m], w8, acc[m][nf], 0, 0, 0);
    }
  }

  // epilogue: C/D layout col=lane&15, row=(lane>>4)*4+reg
#pragma unroll
  for (int m = 0; m < MF; ++m)
#pragma unroll
    for (int nf = 0; nf < NF; ++nf) {
      const size_t r_base = R0 + wm * (64 / WIM) + m * 16 + hi4 * 4;
      const int col = C0 + nf * 16 + lo16;
#pragma unroll
      for (int rr = 0; rr < 4; ++rr)
        out[(r_base + rr) * N_TOT + col] = acc[m][nf][rr];
    }
}

// ---------------- MFMA chunk scan, two passes ----------------
// MODE 0: zero-init local scan; READ-ONLY over U; emits Lst[c][b][:] (last state).
// MODE 1: true scan, init from E[c][b][:] (f32); writes states over U in place.
// 3 independent MFMA accumulator chains (hh/hl/lh) cut the serial dep chain 3x.
template <int MODE>
__global__ __launch_bounds__(1024, 4) void k_mscan(const _Float16* __restrict__ Fhi,
                                                   const _Float16* __restrict__ Flo,
                                                   float* __restrict__ U,
                                                   const float* __restrict__ E,
                                                   float* __restrict__ Lst) {
  __shared__ _Float16 sh[16 * 264];
  __shared__ _Float16 sl[16 * 264];

  const int tid = threadIdx.x;
  const int wv = tid >> 6;
  const int l = tid & 63;
  const int lo16 = l & 15, hi4 = l >> 4;
  const int dcol = wv * 16 + lo16;

  const int c = blockIdx.x >> 2;
  const int b0 = (blockIdx.x & 3) * 16;

  half8v fh[8], fl[8];
#pragma unroll
  for (int kk = 0; kk < 8; ++kk) {
    const size_t fo = (size_t)dcol * 256 + kk * 32 + hi4 * 8;
    fh[kk] = *reinterpret_cast<const half8v*>(Fhi + fo);
    fl[kk] = *reinterpret_cast<const half8v*>(Flo + fo);
  }

  if (MODE == 1) {  // seed state from E (f32)
#pragma unroll
    for (int r = 0; r < 4; ++r) {
      const int m = hi4 * 4 + r;
      float x = E[((size_t)c * BATCH + b0 + m) * 256 + dcol];
      _Float16 h = (_Float16)x;
      sh[m * 264 + dcol] = h;
      sl[m * 264 + dcol] = (_Float16)(x - (float)h);
    }
    __syncthreads();
  }

  const size_t ustr = (size_t)TT * 256;
  float* ub = U + ((size_t)b0 * TT + c * CHUNK) * 256 + dcol;

  float u_cur[4], u_nxt[4];
#pragma unroll
  for (int r = 0; r < 4; ++r) u_cur[r] = ub[(size_t)(hi4 * 4 + r) * ustr];

  for (int k = 0; k < CHUNK; ++k) {
    if (k < CHUNK - 1) {
#pragma unroll
      for (int r = 0; r < 4; ++r)
        u_nxt[r] = ub[(size_t)(hi4 * 4 + r) * ustr + (k + 1) * 256];
    }
    float4v a0, a1, a2;
#pragma unroll
    for (int r = 0; r < 4; ++r) {
      a0[r] = u_cur[r];
      a1[r] = 0.f;
      a2[r] = 0.f;
    }

    if (MODE == 1 || k) {
#pragma unroll
      for (int kk = 0; kk < 8; ++kk) {
        const int ao = lo16 * 264 + kk * 32 + hi4 * 8;
        half8v ah = *reinterpret_cast<const half8v*>(&sh[ao]);
        half8v al = *reinterpret_cast<const half8v*>(&sl[ao]);
        a0 = __builtin_amdgcn_mfma_f32_16x16x32_f16(ah, fh[kk], a0, 0, 0, 0);
        a1 = __builtin_amdgcn_mfma_f32_16x16x32_f16(ah, fl[kk], a1, 0, 0, 0);
        a2 = __builtin_amdgcn_mfma_f32_16x16x32_f16(al, fh[kk], a2, 0, 0, 0);
      }
    }

    _Float16 xh[4], xl[4];
#pragma unroll
    for (int r = 0; r < 4; ++r) {
      float x = a0[r] + a1[r] + a2[r];
      if (MODE == 1) ub[(size_t)(hi4 * 4 + r) * ustr + k * 256] = x;
      if (MODE == 0 && k == CHUNK - 1)
        Lst[((size_t)c * BATCH + b0 + hi4 * 4 + r) * 256 + dcol] = x;
      _Float16 h = (_Float16)x;
      xh[r] = h;
      xl[r] = (_Float16)(x - (float)h);
    }
    __syncthreads();  // all waves done reading sh/sl for step k
#pragma unroll
    for (int r = 0; r < 4; ++r) {
      const int m = hi4 * 4 + r;
      sh[m * 264 + dcol] = xh[r];
      sl[m * 264 + dcol] = xl[r];
    }
    __syncthreads();  // writes visible for step k+1
#pragma unroll
    for (int r = 0; r < 4; ++r) u_cur[r] = u_nxt[r];
  }
}

// ---------------- chunk carry: e_{c+1} = F^32 e_c + Lst[c] -> E (f32) ----------------
__global__ __launch_bounds__(1024, 4) void k_mcarry(const _Float16* __restrict__ FLhi,
                                                    const _Float16* __restrict__ FLlo,
                                                    const float* __restrict__ state0,
                                                    const float* __restrict__ Lst,
                                                    float* __restrict__ E) {
  __shared__ _Float16 sh[16 * 264];
  __shared__ _Float16 sl[16 * 264];

  const int tid = threadIdx.x;
  const int wv = tid >> 6;
  const int l = tid & 63;
  const int lo16 = l & 15, hi4 = l >> 4;
  const int dcol = wv * 16 + lo16;
  const int b0 = blockIdx.x * 16;

  half8v fh[8], fl[8];
#pragma unroll
  for (int kk = 0; kk < 8; ++kk) {
    const size_t fo = (size_t)dcol * 256 + kk * 32 + hi4 * 8;
    fh[kk] = *reinterpret_cast<const half8v*>(FLhi + fo);
    fl[kk] = *reinterpret_cast<const half8v*>(FLlo + fo);
  }

#pragma unroll
  for (int r = 0; r < 4; ++r) {
    const int m = hi4 * 4 + r;
    float x = state0[(size_t)(b0 + m) * 256 + dcol];
    E[(size_t)(b0 + m) * 256 + dcol] = x;  // E[0] = initial state
    _Float16 h = (_Float16)x;
    sh[m * 264 + dcol] = h;
    sl[m * 264 + dcol] = (_Float16)(x - (float)h);
  }
  __syncthreads();

  for (int cstep = 0; cstep < NCHUNK - 1; ++cstep) {
    float4v a0, a1, a2;
#pragma unroll
    for (int r = 0; r < 4; ++r) {
      a0[r] = Lst[((size_t)cstep * BATCH + b0 + hi4 * 4 + r) * 256 + dcol];
      a1[r] = 0.f;
      a2[r] = 0.f;
    }
#pragma unroll
    for (int kk = 0; kk < 8; ++kk) {
      const int ao = lo16 * 264 + kk * 32 + hi4 * 8;
      half8v ah = *reinterpret_cast<const half8v*>(&sh[ao]);
      half8v al = *reinterpret_cast<const half8v*>(&sl[ao]);
      a0 = __builtin_amdgcn_mfma_f32_16x16x32_f16(ah, fh[kk], a0, 0, 0, 0);
      a1 = __builtin_amdgcn_mfma_f32_16x16x32_f16(ah, fl[kk], a1, 0, 0, 0);
      a2 = __builtin_amdgcn_mfma_f32_16x16x32_f16(al, fh[kk], a2, 0, 0, 0);
    }
    _Float16 xh[4], xl[4];
#pragma unroll
    for (int r = 0; r < 4; ++r) {
      float x = a0[r] + a1[r] + a2[r];
      E[((size_t)(cstep + 1) * BATCH + b0 + hi4 * 4 + r) * 256 + dcol] = x;
      _Float16 h = (_Float16)x;
      xh[r] = h;
      xl[r] = (_Float16)(x - (float)h);
    }
    __syncthreads();
#pragma unroll
    for (int r = 0; r < 4; ++r) {
      const int m = hi4 * 4 + r;
      sh[m * 264 + dcol] = xh[r];
      sl[m * 264 + dcol] = xl[r];
    }
    __syncthreads();
  }
}

extern "C" void kernel_launch(void* const* d_in, const int* in_sizes, int n_in,
                              void* d_out, int out_size, void* d_ws, size_t ws_size,
                              hipStream_t stream) {
  const float* state  = (const float*)d_in[0];
  const float* inputs = (const float*)d_in[1];
  const float* eps_W  = (const float*)d_in[2];
  const float* eps_V  = (const float*)d_in[3];
  const float* F      = (const float*)d_in[4];
  const float* B_mat  = (const float*)d_in[5];
  const float* H      = (const float*)d_in[6];
  const float* SW     = (const float*)d_in[7];
  const float* SV     = (const float*)d_in[8];

  float* out = (float*)d_out;
  float* states_out = out;                                 // [64][2048][256]
  float* obs_out = out + (size_t)BATCH * TT * S_DIM;       // [64][2048][64]

  // ws (~730 KB): bf16 weights + fp16 F splits
  unsigned short* ws16 = (unsigned short*)d_ws;
  unsigned short* whi1 = ws16;                 // [256][320] = [B_mat | SW] rows
  unsigned short* whi2 = whi1 + 81920;         // [64][320]  = [H | SV] rows
  _Float16* Fhi  = (_Float16*)(whi2 + 20480);  // [256][256]
  _Float16* Flo  = Fhi + 65536;
  _Float16* FLhi = Flo + 65536;                // (F^32) [256][256]
  _Float16* FLlo = FLhi + 65536;

  // big scratch in the dead obs region (8.7 MB of 33.5 MB)
  float* Lst = obs_out;                                    // [64][64][256] f32 (4 MB)
  float* E   = Lst + (size_t)NCHUNK * BATCH * 256;         // [64][64][256] f32 (4 MB)
  float* Pa  = E + (size_t)NCHUNK * BATCH * 256;           // [256][256] ping
  float* Pb  = Pa + 65536;                                 // [256][256] pong

  // F^32 via 5 squarings
  k_matsq<<<256, 256, 0, stream>>>(F, Pa);    // F^2
  k_matsq<<<256, 256, 0, stream>>>(Pa, Pb);   // F^4
  k_matsq<<<256, 256, 0, stream>>>(Pb, Pa);   // F^8
  k_matsq<<<256, 256, 0, stream>>>(Pa, Pb);   // F^16
  k_matsq<<<256, 256, 0, stream>>>(Pb, Pa);   // F^32

  // fp16 splits for scan/carry matrices
  k_fsplit16<<<256, 256, 0, stream>>>(F, Fhi, Flo);
  k_fsplit16<<<256, 256, 0, stream>>>(Pa, FLhi, FLlo);

  // bf16 weights (K-major concat rows)
  k_wcvt<<<320, 256, 0, stream>>>(B_mat, SW, 64, 256, whi1, 256 * 320);
  k_wcvt<<<80, 256, 0, stream>>>(H, SV, 256, 64, whi2, 64 * 320);

  // U = inputs@B^T + eps_W@SW^T  (single-shot LDS, one barrier)
  k_sgemm<256, true, 1, 4><<<BATCH * TT / 64, 256, 81920, stream>>>(
      eps_W, inputs, whi1, states_out);

  // pass 1: local scans (zero init), READ-ONLY, emit Lst
  k_mscan<0><<<NTASK / 16, 1024, 0, stream>>>(Fhi, Flo, states_out, E, Lst);

  // carry across chunks -> E (f32)
  k_mcarry<<<BATCH / 16, 1024, 0, stream>>>(FLhi, FLlo, state, Lst, E);

  // pass 2: true scans seeded from E, write states in place
  k_mscan<1><<<NTASK / 16, 1024, 0, stream>>>(Fhi, Flo, states_out, E, Lst);

  // observations = states@H^T + eps_V@SV^T  (single-shot LDS, one barrier)
  k_sgemm<64, false, 4, 1><<<BATCH * TT / 64, 256, 81920, stream>>>(
      states_out, eps_V, whi2, obs_out);
}